// Round 6
// baseline (288.264 us; speedup 1.0000x reference)
//
#include <hip/hip_runtime.h>
#include <stdint.h>

#define ENC_D 512
#define ATTN_D 512
#define STR_D 256
#define CELL_D 512
#define BATCH 64
#define SEQ 1024
#define NROWS (BATCH * SEQ)

typedef __bf16 bf16x8 __attribute__((ext_vector_type(8)));
typedef float f32x4 __attribute__((ext_vector_type(4)));

__device__ __forceinline__ unsigned short f2bf(float f) {
    unsigned int u = __float_as_uint(f);
    u += 0x7fffu + ((u >> 16) & 1u);   // RNE
    return (unsigned short)(u >> 16);
}

__device__ __forceinline__ void lds_cp16(void* l, const void* g) {
    __builtin_amdgcn_global_load_lds(
        (const __attribute__((address_space(1))) unsigned int*)g,
        (__attribute__((address_space(3))) unsigned int*)l, 16, 0, 0);
}

// ---------------------------------------------------------------------------
// Kernel 1: WF — bf16(W_enc^T) in FRAGMENT-LINEAR order:
//   granule (16 B) = 8 k-elems of one column; gi = nt*1024 + ks*64 + quad*16 + c
// A 16-col chunk (one nt) is a contiguous 16 KB slab; flat copy into LDS gives
// conflict-free lane-linear ds_read_b128 fragments.
// ---------------------------------------------------------------------------
__global__ __launch_bounds__(256) void k_prep_wt(const float* __restrict__ W,
                                                 unsigned short* __restrict__ WF) {
    __shared__ unsigned short T[64 * 68];      // [n_local][e_local], stride 68
    const int t = threadIdx.x;
    const int ei = blockIdx.x >> 3, ni = blockIdx.x & 7;
    const int e0 = ei * 64, n0 = ni * 64;

#pragma unroll
    for (int i = 0; i < 4; ++i) {
        const int idx = t + i * 256;           // 0..1023
        const int r = idx >> 4, c4 = idx & 15;
        const float4 v = *(const float4*)(W + (size_t)(e0 + r) * ATTN_D + n0 + c4 * 4);
        T[(c4 * 4 + 0) * 68 + r] = f2bf(v.x);
        T[(c4 * 4 + 1) * 68 + r] = f2bf(v.y);
        T[(c4 * 4 + 2) * 68 + r] = f2bf(v.z);
        T[(c4 * 4 + 3) * 68 + r] = f2bf(v.w);
    }
    __syncthreads();

#pragma unroll
    for (int i = 0; i < 2; ++i) {
        const int q = t + i * 256;             // 0..511 granules in this tile
        const int n = q >> 3, ge = q & 7;
        union { unsigned short s[8]; uint4 u; } o;
#pragma unroll
        for (int j = 0; j < 8; ++j) o.s[j] = T[n * 68 + ge * 8 + j];
        const int ng = n0 + n;                 // global column
        const int g = ei * 8 + ge;             // global k-granule (k0 = g*8)
        const int nt = ng >> 4, c = ng & 15;
        const int ks = g >> 2, quad = g & 3;
        const int gi = nt * 1024 + ks * 64 + quad * 16 + c;
        *(uint4*)(WF + (size_t)gi * 8) = o.u;
    }
}

// ---------------------------------------------------------------------------
// Kernel 2a: bias partials. grid (12, 64): jq = 64-row slice of 768 combined
// (str|cell) rows, b = batch. part layout: [jq][b][a].
// ---------------------------------------------------------------------------
__global__ __launch_bounds__(128) void k_bias_part(const float* __restrict__ str,
                                                   const float* __restrict__ cell,
                                                   const float* __restrict__ Wstr,
                                                   const float* __restrict__ Wcell,
                                                   float* __restrict__ part) {
    __shared__ float sj[64];
    const int jq = blockIdx.x, b = blockIdx.y, t = threadIdx.x;
    const float* hvec;
    const float* Wrow;
    if (jq < 4) { hvec = str + b * STR_D + jq * 64;            Wrow = Wstr + (size_t)(jq * 64) * ATTN_D; }
    else        { hvec = cell + b * CELL_D + (jq - 4) * 64;    Wrow = Wcell + (size_t)((jq - 4) * 64) * ATTN_D; }
    if (t < 64) sj[t] = hvec[t];
    __syncthreads();

    f32x4 acc = {0.f, 0.f, 0.f, 0.f};
#pragma unroll 8
    for (int i = 0; i < 64; ++i) {
        const float s = sj[i];
        const float4 wv = *(const float4*)(Wrow + (size_t)i * ATTN_D + t * 4);
        acc[0] += s * wv.x; acc[1] += s * wv.y; acc[2] += s * wv.z; acc[3] += s * wv.w;
    }
    *(f32x4*)(part + (size_t)(jq * BATCH + b) * ATTN_D + t * 4) = acc;
}

// ---------------------------------------------------------------------------
// Kernel 2b: bias finalize
// ---------------------------------------------------------------------------
__global__ __launch_bounds__(256) void k_bias_fin(const float* __restrict__ part,
                                                  const float* __restrict__ b_enc,
                                                  const float* __restrict__ b_str,
                                                  const float* __restrict__ b_cell,
                                                  float* __restrict__ bias) {
    const int idx = blockIdx.x * 256 + threadIdx.x;  // 0..32767
    const int b = idx >> 9, a = idx & 511;
    float s = b_enc[a] + b_str[a] + b_cell[a];
#pragma unroll
    for (int jq = 0; jq < 12; ++jq)
        s += part[(size_t)(jq * BATCH + b) * ATTN_D + a];
    bias[idx] = s;
}

// ---------------------------------------------------------------------------
// Kernel 3: fused scores GEMM. 1024 blocks x 128 threads (2 waves), M=64/block.
// 4 independent blocks/CU in separate barrier domains (staggered phases).
// Wave owns 32 rows (A in regs, 128 VGPR). 32 N-chunks of 16 cols; B dbuf in
// LDS (2x16 KB) via flat async copy of fragment-linear WF; each B-frag feeds
// 2 MFMAs (Mw=2). Lane-linear ds_read_b128 -> zero bank conflicts.
// ---------------------------------------------------------------------------
__global__ __launch_bounds__(128, 2) void k_scores(const float* __restrict__ E,
                                                   const unsigned short* __restrict__ WF,
                                                   const float* __restrict__ bias,
                                                   const float* __restrict__ Wcomb,
                                                   float* __restrict__ scores) {
    __shared__ unsigned short buf[2][8192];     // 2 x 16 KB

    const int tid = threadIdx.x;
    const int r0 = blockIdx.x * 64;
    const int b = blockIdx.x >> 4;              // 16 blocks per batch
    const int w = tid >> 6, lane = tid & 63;
    const int quad = lane >> 4, c = lane & 15;

    // stage chunk 0 (async, 16 KB = 8 issues x 128 thr x 16 B)
#pragma unroll
    for (int i = 0; i < 8; ++i)
        lds_cp16((char*)&buf[0][0] + i * 2048 + tid * 16,
                 (const char*)WF + i * 2048 + tid * 16);

    // load A: 2 M-tiles x full K in registers (E read exactly once)
    bf16x8 afr[2][16];
#pragma unroll
    for (int m = 0; m < 2; ++m) {
        const float* Ep = E + (size_t)(r0 + w * 32 + m * 16 + c) * ENC_D + quad * 8;
#pragma unroll
        for (int ks = 0; ks < 16; ++ks) {
            const float4 v0 = *(const float4*)(Ep + ks * 32);
            const float4 v1 = *(const float4*)(Ep + ks * 32 + 4);
            union { unsigned short s[8]; bf16x8 v; } u;
            u.s[0] = f2bf(v0.x); u.s[1] = f2bf(v0.y);
            u.s[2] = f2bf(v0.z); u.s[3] = f2bf(v0.w);
            u.s[4] = f2bf(v1.x); u.s[5] = f2bf(v1.y);
            u.s[6] = f2bf(v1.z); u.s[7] = f2bf(v1.w);
            afr[m][ks] = u.v;
        }
    }

    float sc0[4] = {0.f, 0.f, 0.f, 0.f};
    float sc1[4] = {0.f, 0.f, 0.f, 0.f};
    const float* biasb = bias + b * ATTN_D;

    __syncthreads();   // chunk 0 staged

    for (int ch = 0; ch < 32; ++ch) {
        if (ch < 31) {
            const char* gsrc = (const char*)WF + (size_t)(ch + 1) * 16384;
            char* ldst = (char*)&buf[(ch + 1) & 1][0];
#pragma unroll
            for (int i = 0; i < 8; ++i)
                lds_cp16(ldst + i * 2048 + tid * 16, gsrc + i * 2048 + tid * 16);
        }

        const unsigned short* wb = &buf[ch & 1][0];
        f32x4 a0 = {0.f, 0.f, 0.f, 0.f}, a1 = {0.f, 0.f, 0.f, 0.f};
#pragma unroll
        for (int ks = 0; ks < 16; ++ks) {
            const bf16x8 b0 = *(const bf16x8*)(wb + (ks * 64 + lane) * 8);
            a0 = __builtin_amdgcn_mfma_f32_16x16x32_bf16(afr[0][ks], b0, a0, 0, 0, 0);
            a1 = __builtin_amdgcn_mfma_f32_16x16x32_bf16(afr[1][ks], b0, a1, 0, 0, 0);
        }

        const int n = ch * 16 + c;
        const float bi = biasb[n], wc = Wcomb[n];
#pragma unroll
        for (int r = 0; r < 4; ++r) {
            float v;
            v = a0[r] + bi; sc0[r] += (v > 0.f ? v : 0.f) * wc;
            v = a1[r] + bi; sc1[r] += (v > 0.f ? v : 0.f) * wc;
        }
        __syncthreads();
    }

    // reduce across the 16 column-lanes
#pragma unroll
    for (int r = 0; r < 4; ++r) {
        float v0 = sc0[r], v1 = sc1[r];
        v0 += __shfl_xor(v0, 1); v1 += __shfl_xor(v1, 1);
        v0 += __shfl_xor(v0, 2); v1 += __shfl_xor(v1, 2);
        v0 += __shfl_xor(v0, 4); v1 += __shfl_xor(v1, 4);
        sc0[r] = v0 + __shfl_xor(v0, 8);
        sc1[r] = v1 + __shfl_xor(v1, 8);
    }
    if (c == 0) {
        const int g0 = r0 + w * 32 + quad * 4;
#pragma unroll
        for (int r = 0; r < 4; ++r) scores[g0 + r] = sc0[r];
#pragma unroll
        for (int r = 0; r < 4; ++r) scores[g0 + 16 + r] = sc1[r];
    }
}

// ---------------------------------------------------------------------------
// Kernel 4: softmax over L=1024 per batch (in place)
// ---------------------------------------------------------------------------
__global__ __launch_bounds__(256) void k_softmax(float* __restrict__ s) {
    __shared__ float red[256];
    const int b = blockIdx.x, t = threadIdx.x;
    float v[4];
    float m = -1e30f;
#pragma unroll
    for (int i = 0; i < 4; ++i) {
        v[i] = s[b * SEQ + i * 256 + t];
        m = fmaxf(m, v[i]);
    }
    red[t] = m;
    __syncthreads();
    for (int o = 128; o > 0; o >>= 1) {
        if (t < o) red[t] = fmaxf(red[t], red[t + o]);
        __syncthreads();
    }
    m = red[0];
    __syncthreads();
    float sum = 0.f;
#pragma unroll
    for (int i = 0; i < 4; ++i) {
        v[i] = __expf(v[i] - m);
        sum += v[i];
    }
    red[t] = sum;
    __syncthreads();
    for (int o = 128; o > 0; o >>= 1) {
        if (t < o) red[t] += red[t + o];
        __syncthreads();
    }
    const float inv = 1.f / red[0];
#pragma unroll
    for (int i = 0; i < 4; ++i) s[b * SEQ + i * 256 + t] = v[i] * inv;
}

// ---------------------------------------------------------------------------
// Kernel 5: context partials. 1024 blocks x 128 threads, 64 L-rows per block.
// ---------------------------------------------------------------------------
__global__ __launch_bounds__(128) void k_context(const float* __restrict__ E,
                                                 const float* __restrict__ wts,
                                                 float* __restrict__ part) {
    __shared__ float wl[64];
    const int blk = blockIdx.x, t = threadIdx.x;
    const int b = blk >> 4, lo = blk & 15;
    if (t < 64) wl[t] = wts[b * SEQ + lo * 64 + t];
    __syncthreads();
    const float* Ep = E + ((size_t)(b * SEQ + lo * 64)) * ENC_D + t * 4;
    f32x4 acc = {0.f, 0.f, 0.f, 0.f};
#pragma unroll 8
    for (int l = 0; l < 64; ++l) {
        const float4 v = *(const float4*)(Ep + (size_t)l * ENC_D);
        const float wv = wl[l];
        acc[0] += wv * v.x; acc[1] += wv * v.y;
        acc[2] += wv * v.z; acc[3] += wv * v.w;
    }
    *(f32x4*)(&part[(size_t)(b * 16 + lo) * ENC_D + t * 4]) = acc;
}

// ---------------------------------------------------------------------------
// Kernel 6: reduce 16 L-chunk partials -> out[b][e]
// ---------------------------------------------------------------------------
__global__ __launch_bounds__(256) void k_reduce(const float* __restrict__ part,
                                                float* __restrict__ out) {
    const int idx = blockIdx.x * 256 + threadIdx.x;  // 0..32767
    const int b = idx >> 9, e = idx & 511;
    const float* p = part + (size_t)b * 16 * ENC_D + e;
    float s = 0.f;
#pragma unroll
    for (int i = 0; i < 16; ++i) s += p[i * ENC_D];
    out[idx] = s;
}

// ---------------------------------------------------------------------------
extern "C" void kernel_launch(void* const* d_in, const int* in_sizes, int n_in,
                              void* d_out, int out_size, void* d_ws, size_t ws_size,
                              hipStream_t stream) {
    const float* E      = (const float*)d_in[0];
    const float* str    = (const float*)d_in[1];
    const float* cell   = (const float*)d_in[2];
    const float* Wenc   = (const float*)d_in[3];
    const float* b_enc  = (const float*)d_in[4];
    const float* Wstr   = (const float*)d_in[5];
    const float* b_str  = (const float*)d_in[6];
    const float* Wcell  = (const float*)d_in[7];
    const float* b_cell = (const float*)d_in[8];
    const float* Wcomb  = (const float*)d_in[9];
    // d_in[10] = b_comb: uniform pre-softmax shift — no effect, skipped.
    float* out = (float*)d_out;

    char* ws = (char*)d_ws;
    unsigned short* WF = (unsigned short*)ws;                 // 512 KB (frag-linear)
    float* bias   = (float*)(ws + (512 << 10));               // 128 KB
    float* scores = (float*)(ws + (512 << 10) + (128 << 10)); // 256 KB
    float* part   = (float*)(ws + (512 << 10) + (128 << 10) + (256 << 10)); // 2 MB
    float* bpart  = part;   // bias partials reuse 'part' (k_context runs later)

    k_prep_wt<<<64, 256, 0, stream>>>(Wenc, WF);
    k_bias_part<<<dim3(12, 64), 128, 0, stream>>>(str, cell, Wstr, Wcell, bpart);
    k_bias_fin<<<128, 256, 0, stream>>>(bpart, b_enc, b_str, b_cell, bias);
    k_scores<<<NROWS / 64, 128, 0, stream>>>(E, WF, bias, Wcomb, scores);
    k_softmax<<<BATCH, 256, 0, stream>>>(scores);
    k_context<<<1024, 128, 0, stream>>>(E, scores, part);
    k_reduce<<<NROWS / 512, 256, 0, stream>>>(part, out);
}